// Round 7
// baseline (320.886 us; speedup 1.0000x reference)
//
#include <hip/hip_runtime.h>
#include <hip/hip_fp16.h>

// ---------------------------------------------------------------------------
// EdgeClassifierGNN: 2x GCNConv (128->64->64, sym-norm, self-loops) + edge MLP
// Round 14: R13 failed correctness -- the output block did
// __shfl(ev, 16n+li) INSIDE if(g==0): source lanes 16..63 are inactive there
// and ds_bpermute from inactive lanes is undefined -> 3/4 of outputs scattered
// to garbage edge ids (absmax 1.96). Fix: save the per-tile edge ids in the
// all-lanes-active bh-hoist loop (eo[4]); only the guarded store diverges.
// R13's CSR-order locality design otherwise unchanged: walk edges dst-sorted
// so Pd stage rows repeat (avg degree 16 -> L1/L2 hits), ea gathered by eid,
// out scattered by eid. Counted vmcnt 8/8/4/0 triple-buffer pipeline.
// ---------------------------------------------------------------------------

typedef float v4f __attribute__((ext_vector_type(4)));
typedef _Float16 v4h __attribute__((ext_vector_type(4)));

__device__ __forceinline__ void fma4(float4& a, float s, const float4& b) {
    a.x = fmaf(s, b.x, a.x);
    a.y = fmaf(s, b.y, a.y);
    a.z = fmaf(s, b.z, a.z);
    a.w = fmaf(s, b.w, a.w);
}

__device__ __forceinline__ float4 relu4(float4 v) {
    v.x = fmaxf(v.x, 0.f); v.y = fmaxf(v.y, 0.f);
    v.z = fmaxf(v.z, 0.f); v.w = fmaxf(v.w, 0.f);
    return v;
}

__device__ __forceinline__ void store4(float* C, size_t idx, float4 v) {
    *reinterpret_cast<float4*>(C + idx) = v;
}
__device__ __forceinline__ void store4(__half* C, size_t idx, float4 v) {
    __half2 lo = __floats2half2_rn(v.x, v.y);
    __half2 hi = __floats2half2_rn(v.z, v.w);
    uint2 raw;
    raw.x = *reinterpret_cast<unsigned*>(&lo);
    raw.y = *reinterpret_cast<unsigned*>(&hi);
    *reinterpret_cast<uint2*>(C + idx) = raw;
}

// async global -> LDS, 16B per lane
__device__ __forceinline__ void load_lds16(const void* g, void* l) {
    __builtin_amdgcn_global_load_lds(
        (const __attribute__((address_space(1))) void*)g,
        (__attribute__((address_space(3))) void*)l, 16, 0, 0);
}

// cnt[d]++ per edge; rank[e] = arrival order of e within its dst bucket
__global__ void k_count(const int* __restrict__ dst, int* __restrict__ cnt,
                        int* __restrict__ rank, int E) {
    int e = blockIdx.x * 256 + threadIdx.x;
    if (e < E) rank[e] = atomicAdd(&cnt[dst[e]], 1);
}

// block sums for scan + dinv = rsqrt(cnt+1) (fused)
__global__ void k_bsum(const int* __restrict__ cnt, int* __restrict__ bsum,
                       float* __restrict__ dinv, int N) {
    int i = blockIdx.x * 256 + threadIdx.x;
    int v = (i < N) ? cnt[i] : 0;
    if (i < N) dinv[i] = rsqrtf((float)v + 1.0f);
    int r = v;
#pragma unroll
    for (int d = 1; d < 64; d <<= 1) r += __shfl_xor(r, d);
    __shared__ int ws[4];
    if ((threadIdx.x & 63) == 0) ws[threadIdx.x >> 6] = r;
    __syncthreads();
    if (threadIdx.x == 0) bsum[blockIdx.x] = ws[0] + ws[1] + ws[2] + ws[3];
}

// in-place exclusive scan of bsum[0..nb), nb <= 256, single block
__global__ void k_scanb(int* __restrict__ bsum, int nb) {
    int t = threadIdx.x;
    int lane = t & 63, w = t >> 6;
    int v = (t < nb) ? bsum[t] : 0;
    int x = v;
#pragma unroll
    for (int d = 1; d < 64; d <<= 1) {
        int y = __shfl_up(x, d);
        if (lane >= d) x += y;
    }
    __shared__ int ws[4];
    if (lane == 63) ws[w] = x;
    __syncthreads();
    int woff = 0;
    for (int j = 0; j < w; j++) woff += ws[j];
    if (t < nb) bsum[t] = woff + x - v;
}

// row_ptr[i] = bsum[blk] + exclusive_scan_within_block(cnt); row_ptr[N] = E
__global__ void k_scan3(const int* __restrict__ cnt, const int* __restrict__ bsum,
                        int* __restrict__ row_ptr, int N, int E) {
    int t = threadIdx.x, b = blockIdx.x;
    int i = b * 256 + t;
    int lane = t & 63, w = t >> 6;
    int v = (i < N) ? cnt[i] : 0;
    int x = v;
#pragma unroll
    for (int d = 1; d < 64; d <<= 1) {
        int y = __shfl_up(x, d);
        if (lane >= d) x += y;
    }
    __shared__ int ws[4];
    if (lane == 63) ws[w] = x;
    __syncthreads();
    int woff = 0;
    for (int j = 0; j < w; j++) woff += ws[j];
    if (i < N) row_ptr[i] = bsum[b] + woff + x - v;
    if (i == 0) row_ptr[N] = E;
}

// atomic-free: pos = row_ptr[dst[e]] + rank[e];
// csr_src[pos] = src[e]; csr_de[pos] = {dst[e], e}
__global__ void k_fill(const int* __restrict__ src, const int* __restrict__ dst,
                       const int* __restrict__ row_ptr, const int* __restrict__ rank,
                       int* __restrict__ csr_src, int2* __restrict__ csr_de, int E) {
    int e = blockIdx.x * 256 + threadIdx.x;
    if (e >= E) return;
    int d = dst[e];
    int pos = row_ptr[d] + rank[e];
    csr_src[pos] = src[e];
    csr_de[pos] = make_int2(d, e);
}

// C[M x 64] = (SCALE? dinv[row] : 1) * (op(A[M x K]) @ B[K x 64]); op=relu if RELU_A
// 32-row tiles, 8 outputs/thread (2 rows x 4 cols), bounded unroll.
template<int K, bool RELU_A, bool SCALE, typename OutT>
__global__ __launch_bounds__(256) void k_gemm(const float* __restrict__ A,
                                              const float* __restrict__ B,
                                              const float* __restrict__ dinv,
                                              OutT* __restrict__ C, int M) {
    constexpr int AS = K + 4;
    __shared__ float As[32 * AS];
    __shared__ float Bs[64 * 64];
    const int t = threadIdx.x;
    const int r0 = blockIdx.x * 32;

    constexpr int C4 = K / 4;
    for (int idx = t; idx < 32 * C4; idx += 256) {
        int row = idx / C4, c4 = idx % C4;
        float4 v = make_float4(0.f, 0.f, 0.f, 0.f);
        if (r0 + row < M)
            v = reinterpret_cast<const float4*>(A + (size_t)(r0 + row) * K)[c4];
        if (RELU_A) v = relu4(v);
        *reinterpret_cast<float4*>(&As[row * AS + 4 * c4]) = v;
    }

    const int tx = t & 15, ty = t >> 4;
    float4 acc[2];
    acc[0] = acc[1] = make_float4(0.f, 0.f, 0.f, 0.f);

    for (int c = 0; c < K / 64; c++) {
        __syncthreads();
        for (int idx = t; idx < 64 * 16; idx += 256)
            reinterpret_cast<float4*>(Bs)[idx] =
                reinterpret_cast<const float4*>(B + (size_t)c * 64 * 64)[idx];
        __syncthreads();
#pragma unroll 4
        for (int k0 = 0; k0 < 64; k0 += 4) {
            float4 b0 = *reinterpret_cast<const float4*>(&Bs[(k0 + 0) * 64 + 4 * tx]);
            float4 b1 = *reinterpret_cast<const float4*>(&Bs[(k0 + 1) * 64 + 4 * tx]);
            float4 b2 = *reinterpret_cast<const float4*>(&Bs[(k0 + 2) * 64 + 4 * tx]);
            float4 b3 = *reinterpret_cast<const float4*>(&Bs[(k0 + 3) * 64 + 4 * tx]);
#pragma unroll
            for (int i = 0; i < 2; i++) {
                float4 a = *reinterpret_cast<const float4*>(
                    &As[(2 * ty + i) * AS + c * 64 + k0]);
                fma4(acc[i], a.x, b0);
                fma4(acc[i], a.y, b1);
                fma4(acc[i], a.z, b2);
                fma4(acc[i], a.w, b3);
            }
        }
    }

#pragma unroll
    for (int i = 0; i < 2; i++) {
        int row = r0 + 2 * ty + i;
        if (row < M) {
            float4 o = acc[i];
            if (SCALE) {
                float di = dinv[row];
                o = make_float4(di * o.x, di * o.y, di * o.z, di * o.w);
            }
            store4(C, (size_t)row * 64 + 4 * tx, o);
        }
    }
}

// Fused projections: C0 = relu(A)@B0 + bias, C1 = relu(A)@B1, fp16 out.
// 32-row tiles, 8 outputs/thread per matrix, bounded unroll.
__global__ __launch_bounds__(256) void k_proj(const float* __restrict__ A,
                                              const float* __restrict__ B0,
                                              const float* __restrict__ B1,
                                              const float* __restrict__ bias,
                                              __half* __restrict__ C0,
                                              __half* __restrict__ C1, int M) {
    constexpr int AS = 68;
    __shared__ float As[32 * AS];
    __shared__ float Bs[64 * 64];
    const int t = threadIdx.x;
    const int r0 = blockIdx.x * 32;

    for (int idx = t; idx < 32 * 16; idx += 256) {
        int row = idx / 16, c4 = idx % 16;
        float4 v = make_float4(0.f, 0.f, 0.f, 0.f);
        if (r0 + row < M)
            v = relu4(reinterpret_cast<const float4*>(A + (size_t)(r0 + row) * 64)[c4]);
        *reinterpret_cast<float4*>(&As[row * AS + 4 * c4]) = v;
    }

    const int tx = t & 15, ty = t >> 4;
    const float4 bb = *reinterpret_cast<const float4*>(&bias[4 * tx]);
    for (int m = 0; m < 2; m++) {
        const float* B = m ? B1 : B0;
        __half* C = m ? C1 : C0;
        __syncthreads();
        for (int idx = t; idx < 64 * 16; idx += 256)
            reinterpret_cast<float4*>(Bs)[idx] =
                reinterpret_cast<const float4*>(B)[idx];
        __syncthreads();
        float4 acc[2];
        acc[0] = acc[1] = make_float4(0.f, 0.f, 0.f, 0.f);
#pragma unroll 4
        for (int k0 = 0; k0 < 64; k0 += 4) {
            float4 b0 = *reinterpret_cast<const float4*>(&Bs[(k0 + 0) * 64 + 4 * tx]);
            float4 b1 = *reinterpret_cast<const float4*>(&Bs[(k0 + 1) * 64 + 4 * tx]);
            float4 b2 = *reinterpret_cast<const float4*>(&Bs[(k0 + 2) * 64 + 4 * tx]);
            float4 b3 = *reinterpret_cast<const float4*>(&Bs[(k0 + 3) * 64 + 4 * tx]);
#pragma unroll
            for (int i = 0; i < 2; i++) {
                float4 a = *reinterpret_cast<const float4*>(&As[(2 * ty + i) * AS + k0]);
                fma4(acc[i], a.x, b0);
                fma4(acc[i], a.y, b1);
                fma4(acc[i], a.z, b2);
                fma4(acc[i], a.w, b3);
            }
        }
#pragma unroll
        for (int i = 0; i < 2; i++) {
            int row = r0 + 2 * ty + i;
            if (row < M) {
                float4 o = acc[i];
                if (m == 0) {  // fold bm1 into Ps so k_edge skips it
                    o.x += bb.x; o.y += bb.y; o.z += bb.z; o.w += bb.w;
                }
                store4(C, (size_t)row * 64 + 4 * tx, o);
            }
        }
    }
}

// 4 nodes/wave, 16 lanes/node, uint2 (4 fp16)/lane, 8-deep gather pipeline:
// out[d] = bias + dinv[d]*(A16[d] + sum_s A16[s])
__global__ __launch_bounds__(256, 4) void k_agg(const __half* __restrict__ A16,
                                                const int* __restrict__ row_ptr,
                                                const int* __restrict__ csr_src,
                                                const float* __restrict__ dinv,
                                                const float* __restrict__ bias,
                                                float* __restrict__ out, int N) {
    int gw = (blockIdx.x * 256 + threadIdx.x) >> 6;  // global wave
    int sub = (threadIdx.x >> 4) & 3;
    int l = threadIdx.x & 15;
    int node = gw * 4 + sub;
    if (node >= N) return;
    const uint2* A4 = reinterpret_cast<const uint2*>(A16);  // row = 16 uint2

    int beg = row_ptr[node], end = row_ptr[node + 1];
    uint2 selfv = A4[(size_t)node * 16 + l];
    float2 a0 = __half22float2(*reinterpret_cast<__half2*>(&selfv.x));
    float2 a1 = __half22float2(*reinterpret_cast<__half2*>(&selfv.y));
    float4 acc = make_float4(a0.x, a0.y, a1.x, a1.y);

#define ACC(u)                                                          \
    {                                                                   \
        float2 f0 = __half22float2(*reinterpret_cast<__half2*>(&u.x));  \
        float2 f1 = __half22float2(*reinterpret_cast<__half2*>(&u.y));  \
        acc.x += f0.x; acc.y += f0.y; acc.z += f1.x; acc.w += f1.y;     \
    }
    for (int p = beg; p < end; p += 16) {
        int m = min(16, end - p);
        int sl = (p + l < end) ? csr_src[p + l] : 0;
        int j = 0;
        for (; j + 7 < m; j += 8) {
            uint2 u0 = A4[(size_t)__shfl(sl, j + 0, 16) * 16 + l];
            uint2 u1 = A4[(size_t)__shfl(sl, j + 1, 16) * 16 + l];
            uint2 u2 = A4[(size_t)__shfl(sl, j + 2, 16) * 16 + l];
            uint2 u3 = A4[(size_t)__shfl(sl, j + 3, 16) * 16 + l];
            uint2 u4 = A4[(size_t)__shfl(sl, j + 4, 16) * 16 + l];
            uint2 u5 = A4[(size_t)__shfl(sl, j + 5, 16) * 16 + l];
            uint2 u6 = A4[(size_t)__shfl(sl, j + 6, 16) * 16 + l];
            uint2 u7 = A4[(size_t)__shfl(sl, j + 7, 16) * 16 + l];
            ACC(u0) ACC(u1) ACC(u2) ACC(u3) ACC(u4) ACC(u5) ACC(u6) ACC(u7)
        }
        for (; j + 3 < m; j += 4) {
            uint2 u0 = A4[(size_t)__shfl(sl, j + 0, 16) * 16 + l];
            uint2 u1 = A4[(size_t)__shfl(sl, j + 1, 16) * 16 + l];
            uint2 u2 = A4[(size_t)__shfl(sl, j + 2, 16) * 16 + l];
            uint2 u3 = A4[(size_t)__shfl(sl, j + 3, 16) * 16 + l];
            ACC(u0) ACC(u1) ACC(u2) ACC(u3)
        }
        for (; j < m; j++) {
            uint2 u0 = A4[(size_t)__shfl(sl, j, 16) * 16 + l];
            ACC(u0)
        }
    }
#undef ACC
    float di = dinv[node];
    float4 bb = *reinterpret_cast<const float4*>(&bias[4 * l]);
    float4 o = make_float4(fmaf(di, acc.x, bb.x), fmaf(di, acc.y, bb.y),
                           fmaf(di, acc.z, bb.z), fmaf(di, acc.w, bb.w));
    *reinterpret_cast<float4*>(&out[(size_t)node * 64 + 4 * l]) = o;
}

// Edge epilogue via MFMA + LDS-staged endpoint rows, triple-buffered, walked
// in CSR (dst-sorted) position order: per wave 64 positions, 4 tiles of 16.
// src/dst/eid come from csr_src/csr_de (coalesced); Pd stage rows repeat
// within a tile (avg degree 16) -> L1/L2 same-line hits; ea gathered by eid
// (64B rows); out scattered by eid (8B). Counted vmcnt 8/8/4/0 pipeline.
// Output edge ids captured in the all-lanes-active region (eo[4]) -- never
// shuffle from potentially-inactive lanes (R13 bug).
__global__ __launch_bounds__(256, 4) void k_edge(
    const __half* __restrict__ Ps, const __half* __restrict__ Pd,
    const int* __restrict__ csr_src, const int2* __restrict__ csr_de,
    const float* __restrict__ ea, const float* __restrict__ We,
    const float* __restrict__ Wm2, const float* __restrict__ bm2,
    float* __restrict__ out, int E) {
    __shared__ __align__(16) char smem[4 * 12288];  // 4 waves x 3 bufs x 4KB
    const int lane = threadIdx.x & 63;
    const int wid = (blockIdx.x * 256 + threadIdx.x) >> 6;
    const int li = lane & 15, g = lane >> 4;
    const int p0 = wid * 64;
    if (p0 >= E) return;

    char* wbase = smem + (threadIdx.x >> 6) * 12288;
    const float4* ea4 = reinterpret_cast<const float4*>(ea);  // row = 4 float4

    // A-frag (We^T): lane holds A[row=li][k=4g+i] of tile m -> We[4g+i][16m+li]
    v4h af[4];
#pragma unroll
    for (int m = 0; m < 4; m++) {
        v4h a;
#pragma unroll
        for (int i = 0; i < 4; i++)
            a[i] = (_Float16)We[(4 * g + i) * 64 + 16 * m + li];
        af[m] = a;
    }

    // Wm2 in the D layout: lane covers dims {16m+4g+r, r=0..3}
    float4 w2lo[4], w2hi[4];
#pragma unroll
    for (int m = 0; m < 4; m++) {
        int dim0 = 16 * m + 4 * g;
        w2lo[m] = *reinterpret_cast<const float4*>(&Wm2[2 * dim0]);      // rows r0,r1
        w2hi[m] = *reinterpret_cast<const float4*>(&Wm2[2 * dim0 + 4]);  // rows r2,r3
    }
    const float c0 = bm2[0], c1 = bm2[1];

    // per-lane CSR position (coalesced), redistributed by shfl
    const int pcl = min(p0 + lane, E - 1);
    const int sv = csr_src[pcl];
    const int2 de = csr_de[pcl];
    const int dv = de.x, ev = de.y;

    // hoist ea B-frags + output edge ids for all 4 tiles BEFORE staging and
    // with ALL lanes active (shfl from inactive lanes is undefined)
    v4h bh[4];
    int eo[4];
#pragma unroll
    for (int n = 0; n < 4; n++) {
        int eid = __shfl(ev, 16 * n + li);
        eo[n] = eid;
        float4 bf = ea4[(size_t)eid * 4 + g];
        v4h t;
        t[0] = (_Float16)bf.x; t[1] = (_Float16)bf.y;
        t[2] = (_Float16)bf.z; t[3] = (_Float16)bf.w;
        bh[n] = t;
    }

    // staging lane decomposition: instr j writes rows 8j..8j+7, lane covers
    // (row = 8j + (l>>3), chunk16 = l&7); fetch global chunk (l&7)^(l>>3)
    const int jrow = lane >> 3;          // 0..7
    const int csw = (lane & 7) ^ jrow;   // pre-swizzled 16B chunk

#define STAGE(n, b)                                                              \
    {                                                                            \
        char* lb = wbase + (b) * 4096 + lane * 16;                               \
        int n0 = __shfl(sv, 16 * (n) + jrow);                                    \
        int n1 = __shfl(sv, 16 * (n) + 8 + jrow);                                \
        int n2 = __shfl(dv, 16 * (n) + jrow);                                    \
        int n3 = __shfl(dv, 16 * (n) + 8 + jrow);                                \
        load_lds16((const char*)Ps + (size_t)n0 * 128 + (csw << 4), lb);         \
        load_lds16((const char*)Ps + (size_t)n1 * 128 + (csw << 4), lb + 1024);  \
        load_lds16((const char*)Pd + (size_t)n2 * 128 + (csw << 4), lb + 2048);  \
        load_lds16((const char*)Pd + (size_t)n3 * 128 + (csw << 4), lb + 3072);  \
    }

    float p0s[4], p1s[4];

#define COMPUTE(n, b)                                                             \
    {                                                                             \
        const char* rb = wbase + (b) * 4096;                                      \
        uint2 us[4], ud[4];                                                       \
        _Pragma("unroll")                                                         \
        for (int m = 0; m < 4; m++) {                                             \
            int q = 4 * m + g;                                                    \
            int off = li * 128 + ((((q >> 1) ^ (li & 7)) << 4) | ((q & 1) << 3)); \
            us[m] = *reinterpret_cast<const uint2*>(rb + off);                    \
            ud[m] = *reinterpret_cast<const uint2*>(rb + 2048 + off);             \
        }                                                                         \
        float p0_ = 0.f, p1_ = 0.f;                                               \
        _Pragma("unroll")                                                         \
        for (int m = 0; m < 4; m++) {                                             \
            float2 s0 = __half22float2(*reinterpret_cast<__half2*>(&us[m].x));    \
            float2 s1 = __half22float2(*reinterpret_cast<__half2*>(&us[m].y));    \
            float2 d0 = __half22float2(*reinterpret_cast<__half2*>(&ud[m].x));    \
            float2 d1 = __half22float2(*reinterpret_cast<__half2*>(&ud[m].y));    \
            v4f c;                                                                \
            c[0] = s0.x + d0.x;                                                   \
            c[1] = s0.y + d0.y;                                                   \
            c[2] = s1.x + d1.x;                                                   \
            c[3] = s1.y + d1.y;                                                   \
            v4f q = __builtin_amdgcn_mfma_f32_16x16x16f16(af[m], bh[n], c, 0, 0, 0); \
            float u0 = fmaxf(q[0], 0.f), u1 = fmaxf(q[1], 0.f);                   \
            float u2 = fmaxf(q[2], 0.f), u3 = fmaxf(q[3], 0.f);                   \
            p0_ += u0 * w2lo[m].x + u1 * w2lo[m].z + u2 * w2hi[m].x + u3 * w2hi[m].z; \
            p1_ += u0 * w2lo[m].y + u1 * w2lo[m].w + u2 * w2hi[m].y + u3 * w2hi[m].w; \
        }                                                                         \
        p0_ += __shfl_xor(p0_, 16); p0_ += __shfl_xor(p0_, 32);                   \
        p1_ += __shfl_xor(p1_, 16); p1_ += __shfl_xor(p1_, 32);                   \
        p0s[n] = p0_; p1s[n] = p1_;                                               \
    }

    STAGE(0, 0)
    STAGE(1, 1)
    STAGE(2, 2)
    asm volatile("s_waitcnt vmcnt(8)" ::: "memory");   // stage 0 landed
    COMPUTE(0, 0)
    STAGE(3, 0)
    asm volatile("s_waitcnt vmcnt(8)" ::: "memory");   // stage 1 landed
    COMPUTE(1, 1)
    asm volatile("s_waitcnt vmcnt(4)" ::: "memory");   // stage 2 landed
    COMPUTE(2, 2)
    asm volatile("s_waitcnt vmcnt(0)" ::: "memory");   // stage 3 landed
    COMPUTE(3, 0)
#undef STAGE
#undef COMPUTE

    if (g == 0) {
#pragma unroll
        for (int n = 0; n < 4; n++) {
            int pos = p0 + 16 * n + li;
            if (pos < E)
                *reinterpret_cast<float2*>(&out[(size_t)eo[n] * 2]) =
                    make_float2(p0s[n] + c0, p1s[n] + c1);
        }
    }
}

static inline size_t align256(size_t x) { return (x + 255) & ~(size_t)255; }

extern "C" void kernel_launch(void* const* d_in, const int* in_sizes, int n_in,
                              void* d_out, int out_size, void* d_ws, size_t ws_size,
                              hipStream_t stream) {
    const float* x = (const float*)d_in[0];
    const int* ei = (const int*)d_in[1];
    const float* ea = (const float*)d_in[2];
    const float* W1 = (const float*)d_in[3];
    const float* b1 = (const float*)d_in[4];
    const float* W2 = (const float*)d_in[5];
    const float* b2 = (const float*)d_in[6];
    const float* Wm1 = (const float*)d_in[7];
    const float* bm1 = (const float*)d_in[8];
    const float* Wm2 = (const float*)d_in[9];
    const float* bm2 = (const float*)d_in[10];

    const int N = in_sizes[0] / 128;  // 50000
    const int E = in_sizes[1] / 2;    // 800000
    const int* src = ei;
    const int* dst = ei + E;
    float* out = (float*)d_out;

    const int NB = (N + 255) / 256;  // scan blocks (196)

    // ws layout (256B-aligned chunks)
    char* p = (char*)d_ws;
    int* cnt = (int*)p;        p += align256((size_t)N * 4);
    int* rank = (int*)p;       p += align256((size_t)E * 4);
    int* row_ptr = (int*)p;    p += align256((size_t)(N + 1) * 4);
    int* bsum = (int*)p;       p += align256((size_t)NB * 4);
    int* csr_src = (int*)p;    p += align256((size_t)E * 4);
    int2* csr_de = (int2*)p;   p += align256((size_t)E * 8);
    float* dinv = (float*)p;   p += align256((size_t)N * 4);
    __half* A16 = (__half*)p;  p += align256((size_t)N * 64 * 2);
    float* B = (float*)p;      p += align256((size_t)N * 64 * 4);
    __half* Ps16 = (__half*)p; p += align256((size_t)N * 64 * 2);
    __half* Pd16 = (__half*)p;

    // ---- CSR build (counting sort by dst; fill is atomic-free) ----
    hipMemsetAsync(cnt, 0, (size_t)N * sizeof(int), stream);
    k_count<<<(E + 255) / 256, 256, 0, stream>>>(dst, cnt, rank, E);
    k_bsum<<<NB, 256, 0, stream>>>(cnt, bsum, dinv, N);
    k_scanb<<<1, 256, 0, stream>>>(bsum, NB);
    k_scan3<<<NB, 256, 0, stream>>>(cnt, bsum, row_ptr, N, E);
    k_fill<<<(E + 255) / 256, 256, 0, stream>>>(src, dst, row_ptr, rank,
                                                csr_src, csr_de, E);

    // ---- Layer 1 ----
    k_gemm<128, false, true, __half><<<(N + 31) / 32, 256, 0, stream>>>(
        x, W1, dinv, A16, N);
    k_agg<<<(N + 15) / 16, 256, 0, stream>>>(A16, row_ptr, csr_src, dinv, b1, B, N);

    // ---- Layer 2 ----
    k_gemm<64, true, true, __half><<<(N + 31) / 32, 256, 0, stream>>>(
        B, W2, dinv, A16, N);
    k_agg<<<(N + 15) / 16, 256, 0, stream>>>(A16, row_ptr, csr_src, dinv, b2, B, N);

    // ---- Edge MLP, decomposed ----
    k_proj<<<(N + 31) / 32, 256, 0, stream>>>(B, Wm1, Wm1 + 64 * 64, bm1,
                                              Ps16, Pd16, N);
    int waves = (E + 63) / 64;
    k_edge<<<(waves + 3) / 4, 256, 0, stream>>>(Ps16, Pd16, csr_src, csr_de, ea,
                                                Wm1 + 128 * 64, Wm2, bm2,
                                                out, E);
}

// Round 8
// 311.990 us; speedup vs baseline: 1.0285x; 1.0285x over previous
//
#include <hip/hip_runtime.h>
#include <hip/hip_fp16.h>

// ---------------------------------------------------------------------------
// EdgeClassifierGNN: 2x GCNConv (128->64->64, sym-norm, self-loops) + edge MLP
// Round 15: R14's CSR-order k_edge REGRESSED (FETCH only -8MB but WRITE +20MB
// scattered out[eid], occ 35->26): reverted to R12's edge-order triple-buffer
// pipeline (best known, 289us). New experiment: k_agg gathers 102MB of random
// 128B rows from a 6.4MB table -- 1.6x the 4MiB per-XCD L2 => thrash, ~2.5TB/s
// L3-bound. Split features into two [N][32] planes (3.2MB each, L2-RESIDENT)
// and aggregate in two half-passes (8 lanes/node, 64B rows). k_gemm epilogue
// writes the two planes; passes write disjoint column halves of B.
// ---------------------------------------------------------------------------

typedef float v4f __attribute__((ext_vector_type(4)));
typedef _Float16 v4h __attribute__((ext_vector_type(4)));

__device__ __forceinline__ void fma4(float4& a, float s, const float4& b) {
    a.x = fmaf(s, b.x, a.x);
    a.y = fmaf(s, b.y, a.y);
    a.z = fmaf(s, b.z, a.z);
    a.w = fmaf(s, b.w, a.w);
}

__device__ __forceinline__ float4 relu4(float4 v) {
    v.x = fmaxf(v.x, 0.f); v.y = fmaxf(v.y, 0.f);
    v.z = fmaxf(v.z, 0.f); v.w = fmaxf(v.w, 0.f);
    return v;
}

__device__ __forceinline__ void store4(float* C, size_t idx, float4 v) {
    *reinterpret_cast<float4*>(C + idx) = v;
}
__device__ __forceinline__ void store4(__half* C, size_t idx, float4 v) {
    __half2 lo = __floats2half2_rn(v.x, v.y);
    __half2 hi = __floats2half2_rn(v.z, v.w);
    uint2 raw;
    raw.x = *reinterpret_cast<unsigned*>(&lo);
    raw.y = *reinterpret_cast<unsigned*>(&hi);
    *reinterpret_cast<uint2*>(C + idx) = raw;
}

// async global -> LDS, 16B per lane
__device__ __forceinline__ void load_lds16(const void* g, void* l) {
    __builtin_amdgcn_global_load_lds(
        (const __attribute__((address_space(1))) void*)g,
        (__attribute__((address_space(3))) void*)l, 16, 0, 0);
}

// cnt[d]++ per edge; rank[e] = arrival order of e within its dst bucket
__global__ void k_count(const int* __restrict__ dst, int* __restrict__ cnt,
                        int* __restrict__ rank, int E) {
    int e = blockIdx.x * 256 + threadIdx.x;
    if (e < E) rank[e] = atomicAdd(&cnt[dst[e]], 1);
}

// block sums for scan + dinv = rsqrt(cnt+1) (fused)
__global__ void k_bsum(const int* __restrict__ cnt, int* __restrict__ bsum,
                       float* __restrict__ dinv, int N) {
    int i = blockIdx.x * 256 + threadIdx.x;
    int v = (i < N) ? cnt[i] : 0;
    if (i < N) dinv[i] = rsqrtf((float)v + 1.0f);
    int r = v;
#pragma unroll
    for (int d = 1; d < 64; d <<= 1) r += __shfl_xor(r, d);
    __shared__ int ws[4];
    if ((threadIdx.x & 63) == 0) ws[threadIdx.x >> 6] = r;
    __syncthreads();
    if (threadIdx.x == 0) bsum[blockIdx.x] = ws[0] + ws[1] + ws[2] + ws[3];
}

// in-place exclusive scan of bsum[0..nb), nb <= 256, single block
__global__ void k_scanb(int* __restrict__ bsum, int nb) {
    int t = threadIdx.x;
    int lane = t & 63, w = t >> 6;
    int v = (t < nb) ? bsum[t] : 0;
    int x = v;
#pragma unroll
    for (int d = 1; d < 64; d <<= 1) {
        int y = __shfl_up(x, d);
        if (lane >= d) x += y;
    }
    __shared__ int ws[4];
    if (lane == 63) ws[w] = x;
    __syncthreads();
    int woff = 0;
    for (int j = 0; j < w; j++) woff += ws[j];
    if (t < nb) bsum[t] = woff + x - v;
}

// row_ptr[i] = bsum[blk] + exclusive_scan_within_block(cnt); row_ptr[N] = E
__global__ void k_scan3(const int* __restrict__ cnt, const int* __restrict__ bsum,
                        int* __restrict__ row_ptr, int N, int E) {
    int t = threadIdx.x, b = blockIdx.x;
    int i = b * 256 + t;
    int lane = t & 63, w = t >> 6;
    int v = (i < N) ? cnt[i] : 0;
    int x = v;
#pragma unroll
    for (int d = 1; d < 64; d <<= 1) {
        int y = __shfl_up(x, d);
        if (lane >= d) x += y;
    }
    __shared__ int ws[4];
    if (lane == 63) ws[w] = x;
    __syncthreads();
    int woff = 0;
    for (int j = 0; j < w; j++) woff += ws[j];
    if (i < N) row_ptr[i] = bsum[b] + woff + x - v;
    if (i == 0) row_ptr[N] = E;
}

// atomic-free: csr_src[row_ptr[dst[e]] + rank[e]] = src[e]
__global__ void k_fill(const int* __restrict__ src, const int* __restrict__ dst,
                       const int* __restrict__ row_ptr, const int* __restrict__ rank,
                       int* __restrict__ csr_src, int E) {
    int e = blockIdx.x * 256 + threadIdx.x;
    if (e >= E) return;
    csr_src[row_ptr[dst[e]] + rank[e]] = src[e];
}

// C[M x 64] = (SCALE? dinv[row] : 1) * (op(A[M x K]) @ B[K x 64]); op=relu if RELU_A
// 32-row tiles, 8 outputs/thread, bounded unroll. SPLIT: write two [M][32]
// planes C (cols 0-31) / C2 (cols 32-63) so the aggregation passes each
// gather from an L2-resident 3.2MB table.
template<int K, bool RELU_A, bool SCALE, bool SPLIT, typename OutT>
__global__ __launch_bounds__(256) void k_gemm(const float* __restrict__ A,
                                              const float* __restrict__ B,
                                              const float* __restrict__ dinv,
                                              OutT* __restrict__ C,
                                              OutT* __restrict__ C2, int M) {
    constexpr int AS = K + 4;
    __shared__ float As[32 * AS];
    __shared__ float Bs[64 * 64];
    const int t = threadIdx.x;
    const int r0 = blockIdx.x * 32;

    constexpr int C4 = K / 4;
    for (int idx = t; idx < 32 * C4; idx += 256) {
        int row = idx / C4, c4 = idx % C4;
        float4 v = make_float4(0.f, 0.f, 0.f, 0.f);
        if (r0 + row < M)
            v = reinterpret_cast<const float4*>(A + (size_t)(r0 + row) * K)[c4];
        if (RELU_A) v = relu4(v);
        *reinterpret_cast<float4*>(&As[row * AS + 4 * c4]) = v;
    }

    const int tx = t & 15, ty = t >> 4;
    float4 acc[2];
    acc[0] = acc[1] = make_float4(0.f, 0.f, 0.f, 0.f);

    for (int c = 0; c < K / 64; c++) {
        __syncthreads();
        for (int idx = t; idx < 64 * 16; idx += 256)
            reinterpret_cast<float4*>(Bs)[idx] =
                reinterpret_cast<const float4*>(B + (size_t)c * 64 * 64)[idx];
        __syncthreads();
#pragma unroll 4
        for (int k0 = 0; k0 < 64; k0 += 4) {
            float4 b0 = *reinterpret_cast<const float4*>(&Bs[(k0 + 0) * 64 + 4 * tx]);
            float4 b1 = *reinterpret_cast<const float4*>(&Bs[(k0 + 1) * 64 + 4 * tx]);
            float4 b2 = *reinterpret_cast<const float4*>(&Bs[(k0 + 2) * 64 + 4 * tx]);
            float4 b3 = *reinterpret_cast<const float4*>(&Bs[(k0 + 3) * 64 + 4 * tx]);
#pragma unroll
            for (int i = 0; i < 2; i++) {
                float4 a = *reinterpret_cast<const float4*>(
                    &As[(2 * ty + i) * AS + c * 64 + k0]);
                fma4(acc[i], a.x, b0);
                fma4(acc[i], a.y, b1);
                fma4(acc[i], a.z, b2);
                fma4(acc[i], a.w, b3);
            }
        }
    }

#pragma unroll
    for (int i = 0; i < 2; i++) {
        int row = r0 + 2 * ty + i;
        if (row < M) {
            float4 o = acc[i];
            if (SCALE) {
                float di = dinv[row];
                o = make_float4(di * o.x, di * o.y, di * o.z, di * o.w);
            }
            if (SPLIT) {
                OutT* P = (tx < 8) ? C : C2;
                store4(P, (size_t)row * 32 + 4 * (tx & 7), o);
            } else {
                store4(C, (size_t)row * 64 + 4 * tx, o);
            }
        }
    }
}

// Fused projections: C0 = relu(A)@B0 + bias, C1 = relu(A)@B1, fp16 out.
// 32-row tiles, 8 outputs/thread per matrix, bounded unroll.
__global__ __launch_bounds__(256) void k_proj(const float* __restrict__ A,
                                              const float* __restrict__ B0,
                                              const float* __restrict__ B1,
                                              const float* __restrict__ bias,
                                              __half* __restrict__ C0,
                                              __half* __restrict__ C1, int M) {
    constexpr int AS = 68;
    __shared__ float As[32 * AS];
    __shared__ float Bs[64 * 64];
    const int t = threadIdx.x;
    const int r0 = blockIdx.x * 32;

    for (int idx = t; idx < 32 * 16; idx += 256) {
        int row = idx / 16, c4 = idx % 16;
        float4 v = make_float4(0.f, 0.f, 0.f, 0.f);
        if (r0 + row < M)
            v = relu4(reinterpret_cast<const float4*>(A + (size_t)(r0 + row) * 64)[c4]);
        *reinterpret_cast<float4*>(&As[row * AS + 4 * c4]) = v;
    }

    const int tx = t & 15, ty = t >> 4;
    const float4 bb = *reinterpret_cast<const float4*>(&bias[4 * tx]);
    for (int m = 0; m < 2; m++) {
        const float* B = m ? B1 : B0;
        __half* C = m ? C1 : C0;
        __syncthreads();
        for (int idx = t; idx < 64 * 16; idx += 256)
            reinterpret_cast<float4*>(Bs)[idx] =
                reinterpret_cast<const float4*>(B)[idx];
        __syncthreads();
        float4 acc[2];
        acc[0] = acc[1] = make_float4(0.f, 0.f, 0.f, 0.f);
#pragma unroll 4
        for (int k0 = 0; k0 < 64; k0 += 4) {
            float4 b0 = *reinterpret_cast<const float4*>(&Bs[(k0 + 0) * 64 + 4 * tx]);
            float4 b1 = *reinterpret_cast<const float4*>(&Bs[(k0 + 1) * 64 + 4 * tx]);
            float4 b2 = *reinterpret_cast<const float4*>(&Bs[(k0 + 2) * 64 + 4 * tx]);
            float4 b3 = *reinterpret_cast<const float4*>(&Bs[(k0 + 3) * 64 + 4 * tx]);
#pragma unroll
            for (int i = 0; i < 2; i++) {
                float4 a = *reinterpret_cast<const float4*>(&As[(2 * ty + i) * AS + k0]);
                fma4(acc[i], a.x, b0);
                fma4(acc[i], a.y, b1);
                fma4(acc[i], a.z, b2);
                fma4(acc[i], a.w, b3);
            }
        }
#pragma unroll
        for (int i = 0; i < 2; i++) {
            int row = r0 + 2 * ty + i;
            if (row < M) {
                float4 o = acc[i];
                if (m == 0) {  // fold bm1 into Ps so k_edge skips it
                    o.x += bb.x; o.y += bb.y; o.z += bb.z; o.w += bb.w;
                }
                store4(C, (size_t)row * 64 + 4 * tx, o);
            }
        }
    }
}

// Half-feature aggregation pass over an L2-resident [N][32] fp16 plane.
// 8 nodes/wave, 8 lanes/node, uint2 (4 fp16)/lane, 8-deep gather pipeline:
// out[node][boff+4l..] = bias + dinv*(A[node] + sum_s A[s]) for 32 columns.
__global__ __launch_bounds__(256, 4) void k_agg32(const __half* __restrict__ A,
                                                  const int* __restrict__ row_ptr,
                                                  const int* __restrict__ csr_src,
                                                  const float* __restrict__ dinv,
                                                  const float* __restrict__ bias,
                                                  int boff,
                                                  float* __restrict__ out, int N) {
    int gw = (blockIdx.x * 256 + threadIdx.x) >> 6;  // global wave
    int sub = (threadIdx.x >> 3) & 7;                // node within wave
    int l = threadIdx.x & 7;                         // lane within node
    int node = gw * 8 + sub;
    if (node >= N) return;
    const uint2* A2 = reinterpret_cast<const uint2*>(A);  // row = 8 uint2

    int beg = row_ptr[node], end = row_ptr[node + 1];
    uint2 selfv = A2[(size_t)node * 8 + l];
    float2 a0 = __half22float2(*reinterpret_cast<__half2*>(&selfv.x));
    float2 a1 = __half22float2(*reinterpret_cast<__half2*>(&selfv.y));
    float4 acc = make_float4(a0.x, a0.y, a1.x, a1.y);

#define ACC(u)                                                          \
    {                                                                   \
        float2 f0 = __half22float2(*reinterpret_cast<__half2*>(&u.x));  \
        float2 f1 = __half22float2(*reinterpret_cast<__half2*>(&u.y));  \
        acc.x += f0.x; acc.y += f0.y; acc.z += f1.x; acc.w += f1.y;     \
    }
    for (int p = beg; p < end; p += 8) {
        int m = min(8, end - p);
        int sl = (p + l < end) ? csr_src[p + l] : 0;
        int j = 0;
        for (; j + 7 < m; j += 8) {
            uint2 u0 = A2[(size_t)__shfl(sl, j + 0, 8) * 8 + l];
            uint2 u1 = A2[(size_t)__shfl(sl, j + 1, 8) * 8 + l];
            uint2 u2 = A2[(size_t)__shfl(sl, j + 2, 8) * 8 + l];
            uint2 u3 = A2[(size_t)__shfl(sl, j + 3, 8) * 8 + l];
            uint2 u4 = A2[(size_t)__shfl(sl, j + 4, 8) * 8 + l];
            uint2 u5 = A2[(size_t)__shfl(sl, j + 5, 8) * 8 + l];
            uint2 u6 = A2[(size_t)__shfl(sl, j + 6, 8) * 8 + l];
            uint2 u7 = A2[(size_t)__shfl(sl, j + 7, 8) * 8 + l];
            ACC(u0) ACC(u1) ACC(u2) ACC(u3) ACC(u4) ACC(u5) ACC(u6) ACC(u7)
        }
        for (; j + 3 < m; j += 4) {
            uint2 u0 = A2[(size_t)__shfl(sl, j + 0, 8) * 8 + l];
            uint2 u1 = A2[(size_t)__shfl(sl, j + 1, 8) * 8 + l];
            uint2 u2 = A2[(size_t)__shfl(sl, j + 2, 8) * 8 + l];
            uint2 u3 = A2[(size_t)__shfl(sl, j + 3, 8) * 8 + l];
            ACC(u0) ACC(u1) ACC(u2) ACC(u3)
        }
        for (; j < m; j++) {
            uint2 u0 = A2[(size_t)__shfl(sl, j, 8) * 8 + l];
            ACC(u0)
        }
    }
#undef ACC
    float di = dinv[node];
    float4 bb = *reinterpret_cast<const float4*>(&bias[boff + 4 * l]);
    float4 o = make_float4(fmaf(di, acc.x, bb.x), fmaf(di, acc.y, bb.y),
                           fmaf(di, acc.z, bb.z), fmaf(di, acc.w, bb.w));
    *reinterpret_cast<float4*>(&out[(size_t)node * 64 + boff + 4 * l]) = o;
}

// Edge epilogue via MFMA + LDS-staged endpoint rows, triple-buffered (R12).
// Per wave: 64 edges (original order), 4 tiles of 16. Per tile: 32 endpoint
// rows (4KB) staged via 4x global_load_lds_dwordx4 (row-coalesced, source-side
// XOR swizzle). 2 tiles in flight (counted vmcnt 8/8/4/0); ea/sv/dv hoisted
// BEFORE stages (vmcnt is FIFO); stores deferred so counts stay exact.
__global__ __launch_bounds__(256, 4) void k_edge(
    const __half* __restrict__ Ps, const __half* __restrict__ Pd,
    const int* __restrict__ src, const int* __restrict__ dst,
    const float* __restrict__ ea, const float* __restrict__ We,
    const float* __restrict__ Wm2, const float* __restrict__ bm2,
    float* __restrict__ out, int E) {
    __shared__ __align__(16) char smem[4 * 12288];  // 4 waves x 3 bufs x 4KB
    const int lane = threadIdx.x & 63;
    const int wid = (blockIdx.x * 256 + threadIdx.x) >> 6;
    const int li = lane & 15, g = lane >> 4;
    const int e0 = wid * 64;
    if (e0 >= E) return;

    char* wbase = smem + (threadIdx.x >> 6) * 12288;
    const float4* ea4 = reinterpret_cast<const float4*>(ea);  // row = 4 float4

    // A-frag (We^T): lane holds A[row=li][k=4g+i] of tile m -> We[4g+i][16m+li]
    v4h af[4];
#pragma unroll
    for (int m = 0; m < 4; m++) {
        v4h a;
#pragma unroll
        for (int i = 0; i < 4; i++)
            a[i] = (_Float16)We[(4 * g + i) * 64 + 16 * m + li];
        af[m] = a;
    }

    // Wm2 in the D layout: lane covers dims {16m+4g+r, r=0..3}
    float4 w2lo[4], w2hi[4];
#pragma unroll
    for (int m = 0; m < 4; m++) {
        int dim0 = 16 * m + 4 * g;
        w2lo[m] = *reinterpret_cast<const float4*>(&Wm2[2 * dim0]);      // rows r0,r1
        w2hi[m] = *reinterpret_cast<const float4*>(&Wm2[2 * dim0 + 4]);  // rows r2,r3
    }
    const float c0 = bm2[0], c1 = bm2[1];

    // per-lane edge indices (coalesced), redistributed by shfl
    const int ecl = min(e0 + lane, E - 1);
    const int sv = src[ecl], dv = dst[ecl];

    // hoist ea B-frags for all 4 tiles BEFORE staging (their conversion's
    // implicit vmcnt wait must not drain the stage queue)
    v4h bh[4];
#pragma unroll
    for (int n = 0; n < 4; n++) {
        int ee = min(e0 + 16 * n + li, E - 1);
        float4 bf = ea4[(size_t)ee * 4 + g];
        v4h t;
        t[0] = (_Float16)bf.x; t[1] = (_Float16)bf.y;
        t[2] = (_Float16)bf.z; t[3] = (_Float16)bf.w;
        bh[n] = t;
    }

    // staging lane decomposition: instr j writes rows 8j..8j+7, lane covers
    // (row = 8j + (l>>3), chunk16 = l&7); fetch global chunk (l&7)^(l>>3)
    const int jrow = lane >> 3;          // 0..7
    const int csw = (lane & 7) ^ jrow;   // pre-swizzled 16B chunk

#define STAGE(n, b)                                                              \
    {                                                                            \
        char* lb = wbase + (b) * 4096 + lane * 16;                               \
        int n0 = __shfl(sv, 16 * (n) + jrow);                                    \
        int n1 = __shfl(sv, 16 * (n) + 8 + jrow);                                \
        int n2 = __shfl(dv, 16 * (n) + jrow);                                    \
        int n3 = __shfl(dv, 16 * (n) + 8 + jrow);                                \
        load_lds16((const char*)Ps + (size_t)n0 * 128 + (csw << 4), lb);         \
        load_lds16((const char*)Ps + (size_t)n1 * 128 + (csw << 4), lb + 1024);  \
        load_lds16((const char*)Pd + (size_t)n2 * 128 + (csw << 4), lb + 2048);  \
        load_lds16((const char*)Pd + (size_t)n3 * 128 + (csw << 4), lb + 3072);  \
    }

    float p0s[4], p1s[4];

#define COMPUTE(n, b)                                                             \
    {                                                                             \
        const char* rb = wbase + (b) * 4096;                                      \
        uint2 us[4], ud[4];                                                       \
        _Pragma("unroll")                                                         \
        for (int m = 0; m < 4; m++) {                                             \
            int q = 4 * m + g;                                                    \
            int off = li * 128 + ((((q >> 1) ^ (li & 7)) << 4) | ((q & 1) << 3)); \
            us[m] = *reinterpret_cast<const uint2*>(rb + off);                    \
            ud[m] = *reinterpret_cast<const uint2*>(rb + 2048 + off);             \
        }                                                                         \
        float p0_ = 0.f, p1_ = 0.f;                                               \
        _Pragma("unroll")                                                         \
        for (int m = 0; m < 4; m++) {                                             \
            float2 s0 = __half22float2(*reinterpret_cast<__half2*>(&us[m].x));    \
            float2 s1 = __half22float2(*reinterpret_cast<__half2*>(&us[m].y));    \
            float2 d0 = __half22float2(*reinterpret_cast<__half2*>(&ud[m].x));    \
            float2 d1 = __half22float2(*reinterpret_cast<__half2*>(&ud[m].y));    \
            v4f c;                                                                \
            c[0] = s0.x + d0.x;                                                   \
            c[1] = s0.y + d0.y;                                                   \
            c[2] = s1.x + d1.x;                                                   \
            c[3] = s1.y + d1.y;                                                   \
            v4f q = __builtin_amdgcn_mfma_f32_16x16x16f16(af[m], bh[n], c, 0, 0, 0); \
            float u0 = fmaxf(q[0], 0.f), u1 = fmaxf(q[1], 0.f);                   \
            float u2 = fmaxf(q[2], 0.f), u3 = fmaxf(q[3], 0.f);                   \
            p0_ += u0 * w2lo[m].x + u1 * w2lo[m].z + u2 * w2hi[m].x + u3 * w2hi[m].z; \
            p1_ += u0 * w2lo[m].y + u1 * w2lo[m].w + u2 * w2hi[m].y + u3 * w2hi[m].w; \
        }                                                                         \
        p0_ += __shfl_xor(p0_, 16); p0_ += __shfl_xor(p0_, 32);                   \
        p1_ += __shfl_xor(p1_, 16); p1_ += __shfl_xor(p1_, 32);                   \
        p0s[n] = p0_; p1s[n] = p1_;                                               \
    }

    STAGE(0, 0)
    STAGE(1, 1)
    STAGE(2, 2)
    asm volatile("s_waitcnt vmcnt(8)" ::: "memory");   // stage 0 landed
    COMPUTE(0, 0)
    STAGE(3, 0)
    asm volatile("s_waitcnt vmcnt(8)" ::: "memory");   // stage 1 landed
    COMPUTE(1, 1)
    asm volatile("s_waitcnt vmcnt(4)" ::: "memory");   // stage 2 landed
    COMPUTE(2, 2)
    asm volatile("s_waitcnt vmcnt(0)" ::: "memory");   // stage 3 landed
    COMPUTE(3, 0)
#undef STAGE
#undef COMPUTE

    if (g == 0) {
#pragma unroll
        for (int n = 0; n < 4; n++) {
            int e = e0 + 16 * n + li;
            if (e < E)
                *reinterpret_cast<float2*>(&out[(size_t)e * 2]) =
                    make_float2(p0s[n] + c0, p1s[n] + c1);
        }
    }
}

static inline size_t align256(size_t x) { return (x + 255) & ~(size_t)255; }

extern "C" void kernel_launch(void* const* d_in, const int* in_sizes, int n_in,
                              void* d_out, int out_size, void* d_ws, size_t ws_size,
                              hipStream_t stream) {
    const float* x = (const float*)d_in[0];
    const int* ei = (const int*)d_in[1];
    const float* ea = (const float*)d_in[2];
    const float* W1 = (const float*)d_in[3];
    const float* b1 = (const float*)d_in[4];
    const float* W2 = (const float*)d_in[5];
    const float* b2 = (const float*)d_in[6];
    const float* Wm1 = (const float*)d_in[7];
    const float* bm1 = (const float*)d_in[8];
    const float* Wm2 = (const float*)d_in[9];
    const float* bm2 = (const float*)d_in[10];

    const int N = in_sizes[0] / 128;  // 50000
    const int E = in_sizes[1] / 2;    // 800000
    const int* src = ei;
    const int* dst = ei + E;
    float* out = (float*)d_out;

    const int NB = (N + 255) / 256;  // scan blocks (196)

    // ws layout (256B-aligned chunks)
    char* p = (char*)d_ws;
    int* cnt = (int*)p;         p += align256((size_t)N * 4);
    int* rank = (int*)p;        p += align256((size_t)E * 4);
    int* row_ptr = (int*)p;     p += align256((size_t)(N + 1) * 4);
    int* bsum = (int*)p;        p += align256((size_t)NB * 4);
    int* csr_src = (int*)p;     p += align256((size_t)E * 4);
    float* dinv = (float*)p;    p += align256((size_t)N * 4);
    __half* A16a = (__half*)p;  p += align256((size_t)N * 32 * 2);
    __half* A16b = (__half*)p;  p += align256((size_t)N * 32 * 2);
    float* B = (float*)p;       p += align256((size_t)N * 64 * 4);
    __half* Ps16 = (__half*)p;  p += align256((size_t)N * 64 * 2);
    __half* Pd16 = (__half*)p;

    // ---- CSR build (counting sort by dst; fill is atomic-free) ----
    hipMemsetAsync(cnt, 0, (size_t)N * sizeof(int), stream);
    k_count<<<(E + 255) / 256, 256, 0, stream>>>(dst, cnt, rank, E);
    k_bsum<<<NB, 256, 0, stream>>>(cnt, bsum, dinv, N);
    k_scanb<<<1, 256, 0, stream>>>(bsum, NB);
    k_scan3<<<NB, 256, 0, stream>>>(cnt, bsum, row_ptr, N, E);
    k_fill<<<(E + 255) / 256, 256, 0, stream>>>(src, dst, row_ptr, rank, csr_src, E);

    const int AGG_B = (N + 31) / 32;  // 32 nodes/block

    // ---- Layer 1 ----
    k_gemm<128, false, true, true, __half><<<(N + 31) / 32, 256, 0, stream>>>(
        x, W1, dinv, A16a, A16b, N);
    k_agg32<<<AGG_B, 256, 0, stream>>>(A16a, row_ptr, csr_src, dinv, b1, 0, B, N);
    k_agg32<<<AGG_B, 256, 0, stream>>>(A16b, row_ptr, csr_src, dinv, b1, 32, B, N);

    // ---- Layer 2 ----
    k_gemm<64, true, true, true, __half><<<(N + 31) / 32, 256, 0, stream>>>(
        B, W2, dinv, A16a, A16b, N);
    k_agg32<<<AGG_B, 256, 0, stream>>>(A16a, row_ptr, csr_src, dinv, b2, 0, B, N);
    k_agg32<<<AGG_B, 256, 0, stream>>>(A16b, row_ptr, csr_src, dinv, b2, 32, B, N);

    // ---- Edge MLP, decomposed ----
    k_proj<<<(N + 31) / 32, 256, 0, stream>>>(B, Wm1, Wm1 + 64 * 64, bm1,
                                              Ps16, Pd16, N);
    int waves = (E + 63) / 64;
    k_edge<<<(waves + 3) / 4, 256, 0, stream>>>(Ps16, Pd16, src, dst, ea,
                                                Wm1 + 128 * 64, Wm2, bm2,
                                                out, E);
}

// Round 9
// 276.414 us; speedup vs baseline: 1.1609x; 1.1287x over previous
//
#include <hip/hip_runtime.h>
#include <hip/hip_fp16.h>

// ---------------------------------------------------------------------------
// EdgeClassifierGNN: 2x GCNConv (128->64->64, sym-norm, self-loops) + edge MLP
// Round 16: R15's k_agg feature-split REGRESSED (312 vs 289: 2x instruction/
// launch overhead, no locality gain -- gathers were already L2/L3-served).
// Reverted to R12 config. New: the 3 fp32 VALU GEMMs (k_gemm x2, k_proj,
// ~55-65us combined for 2 GFLOP) -> one MFMA template k_mgemm using
// mfma_f32_16x16x16_f16 with the fragment layout already proven in k_edge:
// A[row=lane&15][k=4g+i], B[k=4g+i][col=lane&15], D[row=4g+r][col=lane&15].
// A-tile + transposed weights staged fp16 in LDS, fp32 accum, dinv/bias in
// epilogue. 32 MFMA/wave replaces ~2000 scalar FMAs.
// ---------------------------------------------------------------------------

typedef float v4f __attribute__((ext_vector_type(4)));
typedef _Float16 v4h __attribute__((ext_vector_type(4)));

__device__ __forceinline__ float4 relu4(float4 v) {
    v.x = fmaxf(v.x, 0.f); v.y = fmaxf(v.y, 0.f);
    v.z = fmaxf(v.z, 0.f); v.w = fmaxf(v.w, 0.f);
    return v;
}

// async global -> LDS, 16B per lane
__device__ __forceinline__ void load_lds16(const void* g, void* l) {
    __builtin_amdgcn_global_load_lds(
        (const __attribute__((address_space(1))) void*)g,
        (__attribute__((address_space(3))) void*)l, 16, 0, 0);
}

// cnt[d]++ per edge; rank[e] = arrival order of e within its dst bucket
__global__ void k_count(const int* __restrict__ dst, int* __restrict__ cnt,
                        int* __restrict__ rank, int E) {
    int e = blockIdx.x * 256 + threadIdx.x;
    if (e < E) rank[e] = atomicAdd(&cnt[dst[e]], 1);
}

// block sums for scan + dinv = rsqrt(cnt+1) (fused)
__global__ void k_bsum(const int* __restrict__ cnt, int* __restrict__ bsum,
                       float* __restrict__ dinv, int N) {
    int i = blockIdx.x * 256 + threadIdx.x;
    int v = (i < N) ? cnt[i] : 0;
    if (i < N) dinv[i] = rsqrtf((float)v + 1.0f);
    int r = v;
#pragma unroll
    for (int d = 1; d < 64; d <<= 1) r += __shfl_xor(r, d);
    __shared__ int ws[4];
    if ((threadIdx.x & 63) == 0) ws[threadIdx.x >> 6] = r;
    __syncthreads();
    if (threadIdx.x == 0) bsum[blockIdx.x] = ws[0] + ws[1] + ws[2] + ws[3];
}

// in-place exclusive scan of bsum[0..nb), nb <= 256, single block
__global__ void k_scanb(int* __restrict__ bsum, int nb) {
    int t = threadIdx.x;
    int lane = t & 63, w = t >> 6;
    int v = (t < nb) ? bsum[t] : 0;
    int x = v;
#pragma unroll
    for (int d = 1; d < 64; d <<= 1) {
        int y = __shfl_up(x, d);
        if (lane >= d) x += y;
    }
    __shared__ int ws[4];
    if (lane == 63) ws[w] = x;
    __syncthreads();
    int woff = 0;
    for (int j = 0; j < w; j++) woff += ws[j];
    if (t < nb) bsum[t] = woff + x - v;
}

// row_ptr[i] = bsum[blk] + exclusive_scan_within_block(cnt); row_ptr[N] = E
__global__ void k_scan3(const int* __restrict__ cnt, const int* __restrict__ bsum,
                        int* __restrict__ row_ptr, int N, int E) {
    int t = threadIdx.x, b = blockIdx.x;
    int i = b * 256 + t;
    int lane = t & 63, w = t >> 6;
    int v = (i < N) ? cnt[i] : 0;
    int x = v;
#pragma unroll
    for (int d = 1; d < 64; d <<= 1) {
        int y = __shfl_up(x, d);
        if (lane >= d) x += y;
    }
    __shared__ int ws[4];
    if (lane == 63) ws[w] = x;
    __syncthreads();
    int woff = 0;
    for (int j = 0; j < w; j++) woff += ws[j];
    if (i < N) row_ptr[i] = bsum[b] + woff + x - v;
    if (i == 0) row_ptr[N] = E;
}

// atomic-free: csr_src[row_ptr[dst[e]] + rank[e]] = src[e]
__global__ void k_fill(const int* __restrict__ src, const int* __restrict__ dst,
                       const int* __restrict__ row_ptr, const int* __restrict__ rank,
                       int* __restrict__ csr_src, int E) {
    int e = blockIdx.x * 256 + threadIdx.x;
    if (e >= E) return;
    csr_src[row_ptr[dst[e]] + rank[e]] = src[e];
}

// MFMA GEMM: C[M x 64] = (SCALE? dinv[row]:1) * (op(A[M x K]) @ B[K x 64])
// (+bias on matrix 0 when NB==2). op = relu if RELU_A. fp16 inputs (converted
// at stage), fp32 accum, fp16 out. 64-row tiles, 4 waves, wave w owns rows
// 16w..16w+15. Fragment layout (proven in k_edge): A[row=lane&15][k=4g+i],
// B[k=4g+i][col=lane&15] (weights staged TRANSPOSED: Bs[col][k]),
// D[row=4g+r][col=lane&15].
template<int K, bool RELU_A, bool SCALE, int NB>
__global__ __launch_bounds__(256) void k_mgemm(
    const float* __restrict__ A, const float* __restrict__ B0,
    const float* __restrict__ B1, const float* __restrict__ bias,
    const float* __restrict__ dinv, __half* __restrict__ C0,
    __half* __restrict__ C1, int M) {
    constexpr int P = K + 8;  // LDS pitch in halves (breaks pow2 bank stride)
    __shared__ __half As[64 * P];
    __shared__ __half Bs[NB * 64 * P];
    const int t = threadIdx.x;
    const int r0 = blockIdx.x * 64;

    // stage A tile (fp32 -> fp16, optional relu), contiguous 8B writes
    constexpr int C4 = K / 4;
    for (int idx = t; idx < 64 * C4; idx += 256) {
        int row = idx / C4, c4 = idx % C4;
        float4 v = make_float4(0.f, 0.f, 0.f, 0.f);
        if (r0 + row < M)
            v = reinterpret_cast<const float4*>(A + (size_t)(r0 + row) * K)[c4];
        if (RELU_A) v = relu4(v);
        __half* d = &As[row * P + 4 * c4];
        d[0] = __float2half(v.x); d[1] = __float2half(v.y);
        d[2] = __float2half(v.z); d[3] = __float2half(v.w);
    }
    // stage weights transposed: Bs[m][col][k]
    for (int m = 0; m < NB; m++) {
        const float* Bm = m ? B1 : B0;
        __half* Bsm = &Bs[m * 64 * P];
        for (int idx = t; idx < K * 16; idx += 256) {
            int k = idx >> 4, c4 = idx & 15;
            float4 v = reinterpret_cast<const float4*>(Bm + (size_t)k * 64)[c4];
            Bsm[(4 * c4 + 0) * P + k] = __float2half(v.x);
            Bsm[(4 * c4 + 1) * P + k] = __float2half(v.y);
            Bsm[(4 * c4 + 2) * P + k] = __float2half(v.z);
            Bsm[(4 * c4 + 3) * P + k] = __float2half(v.w);
        }
    }
    __syncthreads();

    const int lane = t & 63, w = t >> 6;
    const int li = lane & 15, g = lane >> 4;

    v4f acc[NB][4];
    const v4f zero = {0.f, 0.f, 0.f, 0.f};
#pragma unroll
    for (int m = 0; m < NB; m++)
#pragma unroll
        for (int c = 0; c < 4; c++) acc[m][c] = zero;

#pragma unroll
    for (int kk = 0; kk < K; kk += 16) {
        v4h a = *reinterpret_cast<const v4h*>(&As[(16 * w + li) * P + kk + 4 * g]);
#pragma unroll
        for (int m = 0; m < NB; m++) {
#pragma unroll
            for (int c = 0; c < 4; c++) {
                v4h b = *reinterpret_cast<const v4h*>(
                    &Bs[m * 64 * P + (16 * c + li) * P + kk + 4 * g]);
                acc[m][c] =
                    __builtin_amdgcn_mfma_f32_16x16x16f16(a, b, acc[m][c], 0, 0, 0);
            }
        }
    }

    // epilogue: lane holds rows rbase..rbase+3 at col 16c+li
    const int rbase = r0 + 16 * w + 4 * g;
    float4 dv = make_float4(1.f, 1.f, 1.f, 1.f);
    if (SCALE) dv = *reinterpret_cast<const float4*>(&dinv[rbase]);
    const float sc[4] = {dv.x, dv.y, dv.z, dv.w};
#pragma unroll
    for (int m = 0; m < NB; m++) {
        __half* C = m ? C1 : C0;
#pragma unroll
        for (int c = 0; c < 4; c++) {
            int col = 16 * c + li;
            float badd = (NB == 2 && m == 0) ? bias[col] : 0.f;
#pragma unroll
            for (int r = 0; r < 4; r++) {
                int gr = rbase + r;
                if (gr < M)
                    C[(size_t)gr * 64 + col] =
                        __float2half(acc[m][c][r] * sc[r] + badd);
            }
        }
    }
}

// 4 nodes/wave, 16 lanes/node, uint2 (4 fp16)/lane, 8-deep gather pipeline:
// out[d] = bias + dinv[d]*(A16[d] + sum_s A16[s])
__global__ __launch_bounds__(256, 4) void k_agg(const __half* __restrict__ A16,
                                                const int* __restrict__ row_ptr,
                                                const int* __restrict__ csr_src,
                                                const float* __restrict__ dinv,
                                                const float* __restrict__ bias,
                                                float* __restrict__ out, int N) {
    int gw = (blockIdx.x * 256 + threadIdx.x) >> 6;  // global wave
    int sub = (threadIdx.x >> 4) & 3;
    int l = threadIdx.x & 15;
    int node = gw * 4 + sub;
    if (node >= N) return;
    const uint2* A4 = reinterpret_cast<const uint2*>(A16);  // row = 16 uint2

    int beg = row_ptr[node], end = row_ptr[node + 1];
    uint2 selfv = A4[(size_t)node * 16 + l];
    float2 a0 = __half22float2(*reinterpret_cast<__half2*>(&selfv.x));
    float2 a1 = __half22float2(*reinterpret_cast<__half2*>(&selfv.y));
    float4 acc = make_float4(a0.x, a0.y, a1.x, a1.y);

#define ACC(u)                                                          \
    {                                                                   \
        float2 f0 = __half22float2(*reinterpret_cast<__half2*>(&u.x));  \
        float2 f1 = __half22float2(*reinterpret_cast<__half2*>(&u.y));  \
        acc.x += f0.x; acc.y += f0.y; acc.z += f1.x; acc.w += f1.y;     \
    }
    for (int p = beg; p < end; p += 16) {
        int m = min(16, end - p);
        int sl = (p + l < end) ? csr_src[p + l] : 0;
        int j = 0;
        for (; j + 7 < m; j += 8) {
            uint2 u0 = A4[(size_t)__shfl(sl, j + 0, 16) * 16 + l];
            uint2 u1 = A4[(size_t)__shfl(sl, j + 1, 16) * 16 + l];
            uint2 u2 = A4[(size_t)__shfl(sl, j + 2, 16) * 16 + l];
            uint2 u3 = A4[(size_t)__shfl(sl, j + 3, 16) * 16 + l];
            uint2 u4 = A4[(size_t)__shfl(sl, j + 4, 16) * 16 + l];
            uint2 u5 = A4[(size_t)__shfl(sl, j + 5, 16) * 16 + l];
            uint2 u6 = A4[(size_t)__shfl(sl, j + 6, 16) * 16 + l];
            uint2 u7 = A4[(size_t)__shfl(sl, j + 7, 16) * 16 + l];
            ACC(u0) ACC(u1) ACC(u2) ACC(u3) ACC(u4) ACC(u5) ACC(u6) ACC(u7)
        }
        for (; j + 3 < m; j += 4) {
            uint2 u0 = A4[(size_t)__shfl(sl, j + 0, 16) * 16 + l];
            uint2 u1 = A4[(size_t)__shfl(sl, j + 1, 16) * 16 + l];
            uint2 u2 = A4[(size_t)__shfl(sl, j + 2, 16) * 16 + l];
            uint2 u3 = A4[(size_t)__shfl(sl, j + 3, 16) * 16 + l];
            ACC(u0) ACC(u1) ACC(u2) ACC(u3)
        }
        for (; j < m; j++) {
            uint2 u0 = A4[(size_t)__shfl(sl, j, 16) * 16 + l];
            ACC(u0)
        }
    }
#undef ACC
    float di = dinv[node];
    float4 bb = *reinterpret_cast<const float4*>(&bias[4 * l]);
    float4 o = make_float4(fmaf(di, acc.x, bb.x), fmaf(di, acc.y, bb.y),
                           fmaf(di, acc.z, bb.z), fmaf(di, acc.w, bb.w));
    *reinterpret_cast<float4*>(&out[(size_t)node * 64 + 4 * l]) = o;
}

// Edge epilogue via MFMA + LDS-staged endpoint rows, triple-buffered (R12).
// Per wave: 64 edges, 4 tiles of 16. Per tile: 32 endpoint rows (4KB) staged
// via 4x global_load_lds_dwordx4 (row-coalesced, source-side XOR swizzle).
// 2 tiles in flight (counted vmcnt 8/8/4/0); ea/sv/dv hoisted BEFORE stages
// (vmcnt is FIFO); stores deferred so vmcnt counts stay exact.
__global__ __launch_bounds__(256, 4) void k_edge(
    const __half* __restrict__ Ps, const __half* __restrict__ Pd,
    const int* __restrict__ src, const int* __restrict__ dst,
    const float* __restrict__ ea, const float* __restrict__ We,
    const float* __restrict__ Wm2, const float* __restrict__ bm2,
    float* __restrict__ out, int E) {
    __shared__ __align__(16) char smem[4 * 12288];  // 4 waves x 3 bufs x 4KB
    const int lane = threadIdx.x & 63;
    const int wid = (blockIdx.x * 256 + threadIdx.x) >> 6;
    const int li = lane & 15, g = lane >> 4;
    const int e0 = wid * 64;
    if (e0 >= E) return;

    char* wbase = smem + (threadIdx.x >> 6) * 12288;
    const float4* ea4 = reinterpret_cast<const float4*>(ea);  // row = 4 float4

    // A-frag (We^T): lane holds A[row=li][k=4g+i] of tile m -> We[4g+i][16m+li]
    v4h af[4];
#pragma unroll
    for (int m = 0; m < 4; m++) {
        v4h a;
#pragma unroll
        for (int i = 0; i < 4; i++)
            a[i] = (_Float16)We[(4 * g + i) * 64 + 16 * m + li];
        af[m] = a;
    }

    // Wm2 in the D layout: lane covers dims {16m+4g+r, r=0..3}
    float4 w2lo[4], w2hi[4];
#pragma unroll
    for (int m = 0; m < 4; m++) {
        int dim0 = 16 * m + 4 * g;
        w2lo[m] = *reinterpret_cast<const float4*>(&Wm2[2 * dim0]);      // rows r0,r1
        w2hi[m] = *reinterpret_cast<const float4*>(&Wm2[2 * dim0 + 4]);  // rows r2,r3
    }
    const float c0 = bm2[0], c1 = bm2[1];

    // per-lane edge indices (coalesced), redistributed by shfl
    const int ecl = min(e0 + lane, E - 1);
    const int sv = src[ecl], dv = dst[ecl];

    // hoist ea B-frags for all 4 tiles BEFORE staging (their conversion's
    // implicit vmcnt wait must not drain the stage queue)
    v4h bh[4];
#pragma unroll
    for (int n = 0; n < 4; n++) {
        int ee = min(e0 + 16 * n + li, E - 1);
        float4 bf = ea4[(size_t)ee * 4 + g];
        v4h t;
        t[0] = (_Float16)bf.x; t[1] = (_Float16)bf.y;
        t[2] = (_Float16)bf.z; t[3] = (_Float16)bf.w;
        bh[n] = t;
    }

    // staging lane decomposition: instr j writes rows 8j..8j+7, lane covers
    // (row = 8j + (l>>3), chunk16 = l&7); fetch global chunk (l&7)^(l>>3)
    const int jrow = lane >> 3;          // 0..7
    const int csw = (lane & 7) ^ jrow;   // pre-swizzled 16B chunk

#define STAGE(n, b)                                                              \
    {                                                                            \
        char* lb = wbase + (b) * 4096 + lane * 16;                               \
        int n0 = __shfl(sv, 16 * (n) + jrow);                                    \
        int n1 = __shfl(sv, 16 * (n) + 8 + jrow);                                \
        int n2 = __shfl(dv, 16 * (n) + jrow);                                    \
        int n3 = __shfl(dv, 16 * (n) + 8 + jrow);                                \
        load_lds16((const char*)Ps + (size_t)n0 * 128 + (csw << 4), lb);         \
        load_lds16((const char*)Ps + (size_t)n1 * 128 + (csw << 4), lb + 1024);  \
        load_lds16((const char*)Pd + (size_t)n2 * 128 + (csw << 4), lb + 2048);  \
        load_lds16((const char*)Pd + (size_t)n3 * 128 + (csw << 4), lb + 3072);  \
    }

    float p0s[4], p1s[4];

#define COMPUTE(n, b)                                                             \
    {                                                                             \
        const char* rb = wbase + (b) * 4096;                                      \
        uint2 us[4], ud[4];                                                       \
        _Pragma("unroll")                                                         \
        for (int m = 0; m < 4; m++) {                                             \
            int q = 4 * m + g;                                                    \
            int off = li * 128 + ((((q >> 1) ^ (li & 7)) << 4) | ((q & 1) << 3)); \
            us[m] = *reinterpret_cast<const uint2*>(rb + off);                    \
            ud[m] = *reinterpret_cast<const uint2*>(rb + 2048 + off);             \
        }                                                                         \
        float p0_ = 0.f, p1_ = 0.f;                                               \
        _Pragma("unroll")                                                         \
        for (int m = 0; m < 4; m++) {                                             \
            float2 s0 = __half22float2(*reinterpret_cast<__half2*>(&us[m].x));    \
            float2 s1 = __half22float2(*reinterpret_cast<__half2*>(&us[m].y));    \
            float2 d0 = __half22float2(*reinterpret_cast<__half2*>(&ud[m].x));    \
            float2 d1 = __half22float2(*reinterpret_cast<__half2*>(&ud[m].y));    \
            v4f c;                                                                \
            c[0] = s0.x + d0.x;                                                   \
            c[1] = s0.y + d0.y;                                                   \
            c[2] = s1.x + d1.x;                                                   \
            c[3] = s1.y + d1.y;                                                   \
            v4f q = __builtin_amdgcn_mfma_f32_16x16x16f16(af[m], bh[n], c, 0, 0, 0); \
            float u0 = fmaxf(q[0], 0.f), u1 = fmaxf(q[1], 0.f);                   \
            float u2 = fmaxf(q[2], 0.f), u3 = fmaxf(q[3], 0.f);                   \
            p0_ += u0 * w2lo[m].x + u1 * w2lo[m].z + u2 * w2hi[m].x + u3 * w2hi[m].z; \
            p1_ += u0 * w2lo[m].y + u1 * w2lo[m].w + u2 * w2hi[m].y + u3 * w2hi[m].w; \
        }                                                                         \
        p0_ += __shfl_xor(p0_, 16); p0_ += __shfl_xor(p0_, 32);                   \
        p1_ += __shfl_xor(p1_, 16); p1_ += __shfl_xor(p1_, 32);                   \
        p0s[n] = p0_; p1s[n] = p1_;                                               \
    }

    STAGE(0, 0)
    STAGE(1, 1)
    STAGE(2, 2)
    asm volatile("s_waitcnt vmcnt(8)" ::: "memory");   // stage 0 landed
    COMPUTE(0, 0)
    STAGE(3, 0)
    asm volatile("s_waitcnt vmcnt(8)" ::: "memory");   // stage 1 landed
    COMPUTE(1, 1)
    asm volatile("s_waitcnt vmcnt(4)" ::: "memory");   // stage 2 landed
    COMPUTE(2, 2)
    asm volatile("s_waitcnt vmcnt(0)" ::: "memory");   // stage 3 landed
    COMPUTE(3, 0)
#undef STAGE
#undef COMPUTE

    if (g == 0) {
#pragma unroll
        for (int n = 0; n < 4; n++) {
            int e = e0 + 16 * n + li;
            if (e < E)
                *reinterpret_cast<float2*>(&out[(size_t)e * 2]) =
                    make_float2(p0s[n] + c0, p1s[n] + c1);
        }
    }
}

static inline size_t align256(size_t x) { return (x + 255) & ~(size_t)255; }

extern "C" void kernel_launch(void* const* d_in, const int* in_sizes, int n_in,
                              void* d_out, int out_size, void* d_ws, size_t ws_size,
                              hipStream_t stream) {
    const float* x = (const float*)d_in[0];
    const int* ei = (const int*)d_in[1];
    const float* ea = (const float*)d_in[2];
    const float* W1 = (const float*)d_in[3];
    const float* b1 = (const float*)d_in[4];
    const float* W2 = (const float*)d_in[5];
    const float* b2 = (const float*)d_in[6];
    const float* Wm1 = (const float*)d_in[7];
    const float* bm1 = (const float*)d_in[8];
    const float* Wm2 = (const float*)d_in[9];
    const float* bm2 = (const float*)d_in[10];

    const int N = in_sizes[0] / 128;  // 50000
    const int E = in_sizes[1] / 2;    // 800000
    const int* src = ei;
    const int* dst = ei + E;
    float* out = (float*)d_out;

    const int NB = (N + 255) / 256;  // scan blocks (196)

    // ws layout (256B-aligned chunks)
    char* p = (char*)d_ws;
    int* cnt = (int*)p;        p += align256((size_t)N * 4);
    int* rank = (int*)p;       p += align256((size_t)E * 4);
    int* row_ptr = (int*)p;    p += align256((size_t)(N + 1) * 4);
    int* bsum = (int*)p;       p += align256((size_t)NB * 4);
    int* csr_src = (int*)p;    p += align256((size_t)E * 4);
    float* dinv = (float*)p;   p += align256((size_t)N * 4);
    __half* A16 = (__half*)p;  p += align256((size_t)N * 64 * 2);
    float* B = (float*)p;      p += align256((size_t)N * 64 * 4);
    __half* Ps16 = (__half*)p; p += align256((size_t)N * 64 * 2);
    __half* Pd16 = (__half*)p;

    // ---- CSR build (counting sort by dst; fill is atomic-free) ----
    hipMemsetAsync(cnt, 0, (size_t)N * sizeof(int), stream);
    k_count<<<(E + 255) / 256, 256, 0, stream>>>(dst, cnt, rank, E);
    k_bsum<<<NB, 256, 0, stream>>>(cnt, bsum, dinv, N);
    k_scanb<<<1, 256, 0, stream>>>(bsum, NB);
    k_scan3<<<NB, 256, 0, stream>>>(cnt, bsum, row_ptr, N, E);
    k_fill<<<(E + 255) / 256, 256, 0, stream>>>(src, dst, row_ptr, rank, csr_src, E);

    const int GB = (N + 63) / 64;  // 64-row GEMM tiles

    // ---- Layer 1 ----
    k_mgemm<128, false, true, 1><<<GB, 256, 0, stream>>>(
        x, W1, nullptr, nullptr, dinv, A16, nullptr, N);
    k_agg<<<(N + 15) / 16, 256, 0, stream>>>(A16, row_ptr, csr_src, dinv, b1, B, N);

    // ---- Layer 2 ----
    k_mgemm<64, true, true, 1><<<GB, 256, 0, stream>>>(
        B, W2, nullptr, nullptr, dinv, A16, nullptr, N);
    k_agg<<<(N + 15) / 16, 256, 0, stream>>>(A16, row_ptr, csr_src, dinv, b2, B, N);

    // ---- Edge MLP, decomposed ----
    k_mgemm<64, true, false, 2><<<GB, 256, 0, stream>>>(
        B, Wm1, Wm1 + 64 * 64, bm1, nullptr, Ps16, Pd16, N);
    int waves = (E + 63) / 64;
    k_edge<<<(waves + 3) / 4, 256, 0, stream>>>(Ps16, Pd16, src, dst, ea,
                                                Wm1 + 128 * 64, Wm2, bm2,
                                                out, E);
}